// Round 7
// baseline (323.865 us; speedup 1.0000x reference)
//
#include <hip/hip_runtime.h>
#include <hip/hip_bf16.h>
#include <math.h>

// ---------------- problem constants ----------------
#define A_    32
#define B_    32
#define PS    16
#define KK_   9
#define KKA_  288      // KK_*A_
#define OH_   7
#define L_    49
#define NB    4
#define NSITE 196      // NB*L_
#define NCOLS 3136     // NSITE*16

#define LAM1 5.0e-4f        // 0.01*(1-0.95^1)
#define LAM2 9.75e-4f       // 0.01*(1-0.95^2)
#define LAM3 1.42625e-3f    // 0.01*(1-0.95^3)
#define LOG_LN2PI 0.6086775903077413f  // log(log(2*pi))

#define DSTR 33             // dall row stride (floats)

typedef _Float16 half2v __attribute__((ext_vector_type(2)));
typedef short    short8 __attribute__((ext_vector_type(8)));   // 8 bf16 (4 VGPRs)
typedef float    floatx4 __attribute__((ext_vector_type(4)));

static __device__ __forceinline__ float san(float x, float lo, float hi){
    return fminf(fmaxf(x, lo), hi);
}

static __device__ __forceinline__ float dot2acc(half2v a, half2v b, float c){
#if __has_builtin(__builtin_amdgcn_fdot2)
    return __builtin_amdgcn_fdot2(a, b, c, false);
#else
    return c + (float)a.x*(float)b.x + (float)a.y*(float)b.y;
#endif
}

// ================= K1: fused prep (cpr tables + Xt unfold via LDS transpose) =================
// Xt part rewritten (round-6 post-mortem): old version gathered pose with a 12.5 KB
// stride (every lane a separate cache line). New: one block per (bs,q); stage the 32
// pose planes coalesced (784 B contiguous runs) into LDS as bf16, then emit Xt as 16 B
// vector stores along the contiguous `a` dimension. Both sides coalesced.
__global__ void k_prep(const float* __restrict__ fw, const float* __restrict__ pose,
                       ushort* __restrict__ cpr, float* __restrict__ csum,
                       __hip_bfloat16* __restrict__ Xt, int nc)
{
    __shared__ ushort pl[32][200];   // 32 planes of 196 bf16, padded
    if ((int)blockIdx.x < nc){
        int id = (int)blockIdx.x*256 + threadIdx.x;
        if (id >= 16*288) return;
        int p = id / 288, m = id % 288;
        float acc = fw[(0*16 + p)*2 + 0];
        for (int k = 1; k <= 143; ++k){
            float re = fw[(k*16 + p)*2 + 0];
            float im = fw[(k*16 + p)*2 + 1];
            int km = (k*m) % 288;
            float ang = 0.021816615649929116f * (float)km;  // 2*pi/288
            float s, c; __sincosf(ang, &s, &c);
            acc += 2.0f*(re*c - im*s);
        }
        float re144 = fw[(144*16 + p)*2 + 0];
        acc += re144 * ((m & 1) ? -1.0f : 1.0f);
        float cv = acc * (1.0f/288.0f);
        if (m == 0) cv += 1.0f;                            // + identity (residual)
        cv = san(cv, -1e4f, 1e4f);

        __hip_bfloat16 hb = __float2bfloat16(cv);
        float hif = __bfloat162float(hb);
        __hip_bfloat16 lb = __float2bfloat16(cv - hif);
        ushort hi = *(ushort*)&hb, lo = *(ushort*)&lb;

        ushort* c0h = cpr + p*592;
        ushort* c1h = cpr + 16*592   + p*592;
        ushort* c0l = cpr + 16*592*2 + p*592;
        ushort* c1l = cpr + 16*592*3 + p*592;
        int x1 = 288 - m;
        c0h[x1] = hi;  c0l[x1] = lo;
        c1h[x1-1] = hi; c1l[x1-1] = lo;
        if (m >= 1){
            int x2 = 576 - m;
            c0h[x2] = hi;  c0l[x2] = lo;
            c1h[x2-1] = hi; c1l[x2-1] = lo;
        } else {
            c0h[0] = hi; c0l[0] = lo;
            csum[p] = san(1.0f + fw[(0*16 + p)*2 + 0], -1e4f, 1e4f);
        }
        return;
    }
    // ---- Xt: block per (bs,q) ----
    int id2 = (int)blockIdx.x - nc;       // 0..63
    int bs = id2 >> 4, q = id2 & 15;
    int tid = threadIdx.x;
    for (int e = tid; e < 32*196; e += 256){
        int a = e / 196, yx = e % 196;
        float v = pose[(bs*512 + a*16 + q)*196 + yx];   // coalesced along yx
        __hip_bfloat16 hb = __float2bfloat16(san(v, -1e4f, 1e4f));
        pl[a][yx] = *(ushort*)&hb;
    }
    __syncthreads();
    for (int idx = tid; idx < 49*9*4; idx += 256){
        int l = idx / 36, r2 = idx % 36, kk = r2 >> 2, a8 = r2 & 3;
        int oy = l / 7, ox = l % 7;
        int y = oy*2 - 1 + kk/3, x = ox*2 - 1 + kk%3;
        int cc = (bs*49 + l)*16 + q;
        union { ushort us8[8]; uint4 u4; } res;
        if ((unsigned)y < 14u && (unsigned)x < 14u){
            int yx = y*14 + x;
            #pragma unroll
            for (int u = 0; u < 8; ++u) res.us8[u] = pl[a8*8 + u][yx];
        } else {
            res.u4.x = 0; res.u4.y = 0; res.u4.z = 0; res.u4.w = 0;
        }
        *(uint4*)&Xt[cc*KKA_ + kk*32 + a8*8] = res.u4;  // 16B-aligned vector store
    }
}

// ================= K2: MEGA — per-site MFMA GEMM + v + 3 fused EM iterations =================
// Round-6 post-mortem: duration pinned at ~175 µs across 100-260 MB traffic swings ->
// k_mega is LATENCY-bound, not memory-bound; the spill chase was a dead end. The limiter
// is per-thread serial chains at 2 waves/SIMD. This round: 1024 threads (16 waves,
// 4 waves/SIMD) — per-thread serial work halves in every phase:
//  - GEMM: wave w owns p_g = w (1 MFMA chain/wave, 16 waves)
//  - v: thread (c = t&511, h = t>>9) computes pairs h*4..h*4+3 per chunk
//  - phases A/C: half h handles groups h*9..h*9+8; phase B: 32 i-rows/pass, 9 passes
//  - cross-half combines (S1/S2, T0..T2) + mu/i2s broadcast via small LDS arrays
// v stays in global (proven latency-neutral, frees LDS). LDS total 66 KB.
__launch_bounds__(1024, 1)
__global__ void
k_mega(const ushort* __restrict__ cpr, const __hip_bfloat16* __restrict__ Xt,
       const float* __restrict__ a_in,
       const float* __restrict__ mpw, const float* __restrict__ mpb,
       const float* __restrict__ csum,
       const float* __restrict__ beta_u, const float* __restrict__ beta_a,
       uint* __restrict__ vg,
       float* __restrict__ out)
{
    const int nl = blockIdx.x;          // site
    const int t = threadIdx.x;          // 0..1023
    const int c = t & 511;              // v column = (Bc,p)
    const int h = t >> 9;               // i-half (0: groups 0-8, 1: groups 9-17)
    const int Bc = c >> 4, p = c & 15;
    const int bs = nl / L_, l = nl % L_;

    __shared__ __align__(16) _Float16 us[2*4224];   //  16896 B: GEMM double buffer
    __shared__ float dall[288*DSTR];                //  38016 B: d / r, stride 33
    __shared__ float a_s[KKA_];                     //   1152 B
    __shared__ float cst[32];                       //    128 B
    __shared__ float tred[3*512];                   //   6144 B: cross-half partials
    __shared__ float mub[512];                      //   2048 B
    __shared__ float i2b[512];                      //   2048 B  => 66432 B total

    uint* const vgs = vg + (long)nl*144*512 + c;    // this column's v

    // unfold this site's activation row
    for (int j = t; j < KKA_; j += 1024){
        int kk = j >> 5, a = j & 31;
        int oy = l / OH_, ox = l % OH_;
        int y = oy*2 - 1 + kk/3, x = ox*2 - 1 + kk%3;
        float v = 0.f;
        if ((unsigned)y < 14u && (unsigned)x < 14u)
            v = a_in[((bs*A_ + a)*14 + y)*14 + x];
        a_s[j] = san(v, 0.f, 1e4f);
    }
    // per-thread weight row as packed fp16 (column c)
    half2v w_h[8];
    #pragma unroll
    for (int k = 0; k < 8; ++k){
        w_h[k].x = (_Float16)mpw[c*16 + 2*k];
        w_h[k].y = (_Float16)mpw[c*16 + 2*k + 1];
    }
    const float vb = mpb[c] * csum[p];  // bias pushed through the filter
    const float bu = beta_u[Bc];
    const float ba = beta_a[Bc];
    __syncthreads();                    // a_s ready

    // S0tot: 4 accumulators to shorten the dependent-add chain
    float s0a = 0.f, s0b = 0.f, s0c = 0.f, s0d = 0.f;
    for (int j = 0; j < KKA_; j += 4){
        s0a += a_s[j]; s0b += a_s[j+1]; s0c += a_s[j+2]; s0d += a_s[j+3];
    }
    const float S0tot = (s0a + s0b) + (s0c + s0d);

    // ---- GEMM lane mapping: wave w (0..15) owns p_g = w ----
    const int pg = t >> 6, lane = t & 63;
    const int mn = lane & 15, quad = lane >> 4;
    const __hip_bfloat16* xrow = Xt + (nl*16 + mn)*KKA_ + quad*8;

    float S1 = 0.f, S2 = 0.f;

    auto do_chunk = [&](int ch, _Float16* usb){
        floatx4 acc = {0,0,0,0};
        for (int k0i = 0; k0i < 9; ++k0i){
            const int k0 = k0i*32;
            short8 bfrag = *(const short8*)&xrow[k0];
            int o = 288 + k0 + quad*8 - (ch*16 + mn);
            int sel = o & 1, off = o - sel;
            const ushort* bh = cpr + (sel ? 16*592 : 0) + pg*592;
            const ushort* bl = cpr + 16*592*2 + (sel ? 16*592 : 0) + pg*592;
            short8 ah = *(const short8*)&bh[off];
            short8 al = *(const short8*)&bl[off];
            acc = __builtin_amdgcn_mfma_f32_16x16x32_bf16(ah, bfrag, acc, 0, 0, 0);
            acc = __builtin_amdgcn_mfma_f32_16x16x32_bf16(al, bfrag, acc, 0, 0, 0);
        }
        #pragma unroll
        for (int r = 0; r < 4; ++r)
            usb[pg*264 + (quad*4 + r)*16 + mn] = (_Float16)acc[r];
    };

    auto vpair = [&](const _Float16* urow, int s, float& v0o, float& v1o){
        union { uint4 u4; half2v h2[4]; } A0, A1, B0, B1;
        A0.u4 = *(const uint4*)&urow[(2*s)*16];
        A1.u4 = *(const uint4*)&urow[(2*s)*16 + 8];
        B0.u4 = *(const uint4*)&urow[(2*s+1)*16];
        B1.u4 = *(const uint4*)&urow[(2*s+1)*16 + 8];
        float v0 = vb, v1 = vb;
        #pragma unroll
        for (int m = 0; m < 4; ++m){
            v0 = dot2acc(A0.h2[m], w_h[m],   v0);
            v0 = dot2acc(A1.h2[m], w_h[4+m], v0);
            v1 = dot2acc(B0.h2[m], w_h[m],   v1);
            v1 = dot2acc(B1.h2[m], w_h[4+m], v1);
        }
        v0o = v0; v1o = v1;
    };

    // ---- phase 1: 18 chunks, double-buffered us, ONE barrier per chunk ----
    for (int ch = 0; ch < 18; ++ch){
        _Float16* usb = us + (ch & 1)*4224;
        do_chunk(ch, usb);
        __syncthreads();                            // us chunk ready
        const _Float16* urow = &usb[p*264];
        #pragma unroll
        for (int s4 = 0; s4 < 4; ++s4){
            const int s = h*4 + s4;                 // this half's pairs
            float v0, v1; vpair(urow, s, v0, v1);
            const int i0 = ch*16 + 2*s;
            const float a0 = a_s[i0], a1 = a_s[i0+1];
            S1 += a0*v0 + a1*v1;
            S2 += a0*v0*v0 + a1*v1*v1;
            union { half2v hh; uint u; } cv;
            cv.hh.x = (_Float16)v0; cv.hh.y = (_Float16)v1;
            vgs[(ch*8 + s)*512] = cv.u;             // v pair -> global (coalesced)
        }
    }

    // iter-1 m-step (r = 1/32 exactly); combine halves via LDS, publish mu/i2s
    if (h == 1){ tred[c] = S1; tred[512 + c] = S2; }
    __syncthreads();
    float mu_r, i2s_r;
    if (h == 0){
        const float S1t = S1 + tred[c];
        const float S2t = S2 + tred[512 + c];
        const float rs  = S0tot * (1.0f/32.0f);
        const float inv = 1.0f / (rs + 1e-12f);
        const float S1r = S1t * (1.0f/32.0f), S2r = S2t * (1.0f/32.0f);
        const float mu  = S1r * inv;
        const float sg  = fmaxf((S2r - 2.f*mu*S1r + mu*mu*rs) * inv, 0.f) + 1e-12f;
        const float lg  = logf(sg);
        float cs = (bu + 0.5f*lg) * rs;
        float ls = lg + LOG_LN2PI;
        #pragma unroll
        for (int m = 1; m < 16; m <<= 1){ cs += __shfl_xor(cs, m, 16); ls += __shfl_xor(ls, m, 16); }
        const float aout = san(1.f/(1.f + expf(-LAM1*(ba - cs))), 1e-30f, 1.f);
        if (p == 0) cst[Bc] = logf(aout) - 0.5f*ls;
        mub[c] = mu; i2b[c] = 0.5f/sg;
    }
    __syncthreads();                    // publish cst + mu/i2s
    mu_r = mub[c]; i2s_r = i2b[c];

    // ---- iterations 2,3: batched phases ----
    const int b0 = p & 1, b1 = (p>>1)&1, b2 = (p>>2)&1, b3 = (p>>3)&1;
    const int isub2 = t >> 5, Bce = t & 31;
    float muF = 0.f, aF = 0.f;
    for (int it = 0; it < 2; ++it){
        const float lam = it ? LAM3 : LAM2;

        // ---- phase A: this half's 9 groups -> dall[i*DSTR + Bc] ----
        auto dtree = [&](int ibase, const uint* uu){
            float e1[8], e2[4], e3[2], dfin;
            #pragma unroll
            for (int s = 0; s < 8; ++s){
                union { uint u; half2v hh; } cv; cv.u = uu[s];
                float v0 = (float)cv.hh.x, v1 = (float)cv.hh.y;
                float d0 = v0 - mu_r, d1 = v1 - mu_r;
                float ea = d0*d0*i2s_r, eb = d1*d1*i2s_r;
                float aown  = b0 ? eb : ea;
                float asend = b0 ? ea : eb;
                e1[s] = aown + __shfl_xor(asend, 1);
            }
            #pragma unroll
            for (int s = 0; s < 4; ++s){
                float aown  = b1 ? e1[2*s+1] : e1[2*s];
                float asend = b1 ? e1[2*s]   : e1[2*s+1];
                e2[s] = aown + __shfl_xor(asend, 2);
            }
            #pragma unroll
            for (int s = 0; s < 2; ++s){
                float aown  = b2 ? e2[2*s+1] : e2[2*s];
                float asend = b2 ? e2[2*s]   : e2[2*s+1];
                e3[s] = aown + __shfl_xor(asend, 4);
            }
            {
                float aown  = b3 ? e3[1] : e3[0];
                float asend = b3 ? e3[0] : e3[1];
                dfin = aown + __shfl_xor(asend, 8);
            }
            dall[(ibase + p)*DSTR + Bc] = dfin;      // lane p holds d(i = ibase+p)
        };
        for (int g2 = 0; g2 < 9; ++g2){
            const int g = h*9 + g2;
            uint uu[8];
            #pragma unroll
            for (int s = 0; s < 8; ++s) uu[s] = vgs[(g*8 + s)*512];
            dtree(g*16, uu);
        }
        __syncthreads();                             // (1) dall ready

        // ---- phase B: softmax over B, 32 i-rows per pass, 9 passes ----
        {
            const float cb = cst[Bce];
            #pragma unroll
            for (int g2 = 0; g2 < 9; ++g2){
                float* dp = &dall[(g2*32 + isub2)*DSTR + Bce];
                float lnap = cb - *dp;
                float mx = lnap;
                #pragma unroll
                for (int m = 16; m >= 1; m >>= 1) mx = fmaxf(mx, __shfl_xor(mx, m));
                float ex = expf(lnap - mx);
                float sm = ex;
                #pragma unroll
                for (int m = 16; m >= 1; m >>= 1) sm += __shfl_xor(sm, m);
                *dp = (ex / sm) * a_s[g2*32 + isub2];
            }
        }
        __syncthreads();                             // (2) r ready

        // ---- phase C: T sums over this half's groups ----
        float T0 = 0.f, T1 = 0.f, T2 = 0.f;
        for (int g2 = 0; g2 < 9; ++g2){
            const int g = h*9 + g2;
            const int ibase = g*16;
            uint uu[8];
            #pragma unroll
            for (int s = 0; s < 8; ++s) uu[s] = vgs[(g*8 + s)*512];
            #pragma unroll
            for (int s = 0; s < 8; ++s){
                union { uint u; half2v hh; } cv; cv.u = uu[s];
                float v0 = (float)cv.hh.x, v1 = (float)cv.hh.y;
                float r0 = dall[(ibase + 2*s)*DSTR + Bc];
                float r1 = dall[(ibase + 2*s + 1)*DSTR + Bc];
                T0 += r0 + r1;
                T1 += r0*v0 + r1*v1;
                T2 += r0*v0*v0 + r1*v1*v1;
            }
        }
        if (h == 1){ tred[c] = T0; tred[512 + c] = T1; tred[1024 + c] = T2; }
        __syncthreads();                             // partials ready; dall reads done

        if (h == 0){
            T0 += tred[c]; T1 += tred[512 + c]; T2 += tred[1024 + c];
            const float inv = 1.f/(T0 + 1e-12f);
            const float mu  = T1 * inv;
            const float sg  = fmaxf((T2 - 2.f*mu*T1 + mu*mu*T0) * inv, 0.f) + 1e-12f;
            const float lg  = logf(sg);
            float cs = (bu + 0.5f*lg) * T0;
            float ls = lg + LOG_LN2PI;
            #pragma unroll
            for (int m = 1; m < 16; m <<= 1){ cs += __shfl_xor(cs, m, 16); ls += __shfl_xor(ls, m, 16); }
            const float aout = san(1.f/(1.f + expf(-lam*(ba - cs))), 1e-30f, 1.f);
            if (it == 0){
                mub[c] = mu; i2b[c] = 0.5f/sg;
                if (p == 0) cst[Bc] = logf(aout) - 0.5f*ls;
            } else { muF = mu; aF = aout; }
        }
        if (it == 0){
            __syncthreads();                         // publish mu/i2s/cst
            mu_r = mub[c]; i2s_r = i2b[c];
        }
    }

    // ---- outputs (fp32): [a_fin 4*32*49][pose_out 4*512*49] ----
    if (h == 0){
        if (p == 0) out[bs*(B_*L_) + Bc*L_ + l] = san(aF, 0.f, 1.f);
        out[6272 + (bs*512 + c)*L_ + l] = san(muF, -1e4f, 1e4f);
    }
}

// ================= launch =================
extern "C" void kernel_launch(void* const* d_in, const int* in_sizes, int n_in,
                              void* d_out, int out_size, void* d_ws, size_t ws_size,
                              hipStream_t stream)
{
    const float* a_in   = (const float*)d_in[0];
    const float* pose   = (const float*)d_in[1];
    const float* mpw    = (const float*)d_in[2];
    const float* mpb    = (const float*)d_in[3];
    const float* fw     = (const float*)d_in[4];
    // d_in[5..8] (ln_g, ln_b, spat_w, spat_bias) are provably dead: softmax over B of a
    // B-independent gate is exactly 1/B regardless of their values.
    const float* beta_u = (const float*)d_in[9];
    const float* beta_a = (const float*)d_in[10];
    float* out = (float*)d_out;

    // ---- ws layout (byte offsets) ----
    // csum [16] f32              @ 0        (64 B)
    // cpr  4x[16][592] u16       @ 256      (75776 B)
    // Xt   [3136][288] bf16      @ 76288    (1806336 B)
    // vglob [196][144][512] uint @ 1882624  (57802752 B)  -> total ~59.7 MB
    char* base = (char*)d_ws;
    float*  csum = (float*)(base + 0);
    ushort* cpr  = (ushort*)(base + 256);
    __hip_bfloat16* Xt = (__hip_bfloat16*)(base + 76288);
    uint*   vg   = (uint*)(base + 1882624);

    const int nc = 18;
    k_prep<<<nc + 64, 256, 0, stream>>>(fw, pose, cpr, csum, Xt, nc);
    k_mega<<<NSITE, 1024, 0, stream>>>(cpr, Xt, a_in, mpw, mpb, csum, beta_u, beta_a, vg, out);
}

// Round 9
// 316.563 us; speedup vs baseline: 1.0231x; 1.0231x over previous
//
#include <hip/hip_runtime.h>
#include <hip/hip_bf16.h>
#include <math.h>

// ---------------- problem constants ----------------
#define A_    32
#define B_    32
#define PS    16
#define KK_   9
#define KKA_  288      // KK_*A_
#define OH_   7
#define L_    49
#define NB    4
#define NSITE 196      // NB*L_
#define NCOLS 3136     // NSITE*16

#define LAM1 5.0e-4f        // 0.01*(1-0.95^1)
#define LAM2 9.75e-4f       // 0.01*(1-0.95^2)
#define LAM3 1.42625e-3f    // 0.01*(1-0.95^3)
#define LOG_LN2PI 0.6086775903077413f  // log(log(2*pi))

typedef _Float16 half2v __attribute__((ext_vector_type(2)));
typedef short    short8 __attribute__((ext_vector_type(8)));   // 8 bf16 (4 VGPRs)
typedef float    floatx4 __attribute__((ext_vector_type(4)));

static __device__ __forceinline__ float san(float x, float lo, float hi){
    return fminf(fmaxf(x, lo), hi);
}

static __device__ __forceinline__ float dot2acc(half2v a, half2v b, float c){
#if __has_builtin(__builtin_amdgcn_fdot2)
    return __builtin_amdgcn_fdot2(a, b, c, false);
#else
    return c + (float)a.x*(float)b.x + (float)a.y*(float)b.y;
#endif
}

// ================= K1: fused prep (cpr tables + Xt unfold via LDS transpose) =================
__global__ void k_prep(const float* __restrict__ fw, const float* __restrict__ pose,
                       ushort* __restrict__ cpr, float* __restrict__ csum,
                       __hip_bfloat16* __restrict__ Xt, int nc)
{
    __shared__ ushort pl[32][200];   // 32 planes of 196 bf16, padded
    if ((int)blockIdx.x < nc){
        int id = (int)blockIdx.x*256 + threadIdx.x;
        if (id >= 16*288) return;
        int p = id / 288, m = id % 288;
        float acc = fw[(0*16 + p)*2 + 0];
        for (int k = 1; k <= 143; ++k){
            float re = fw[(k*16 + p)*2 + 0];
            float im = fw[(k*16 + p)*2 + 1];
            int km = (k*m) % 288;
            float ang = 0.021816615649929116f * (float)km;  // 2*pi/288
            float s, c; __sincosf(ang, &s, &c);
            acc += 2.0f*(re*c - im*s);
        }
        float re144 = fw[(144*16 + p)*2 + 0];
        acc += re144 * ((m & 1) ? -1.0f : 1.0f);
        float cv = acc * (1.0f/288.0f);
        if (m == 0) cv += 1.0f;                            // + identity (residual)
        cv = san(cv, -1e4f, 1e4f);

        __hip_bfloat16 hb = __float2bfloat16(cv);
        float hif = __bfloat162float(hb);
        __hip_bfloat16 lb = __float2bfloat16(cv - hif);
        ushort hi = *(ushort*)&hb, lo = *(ushort*)&lb;

        ushort* c0h = cpr + p*592;
        ushort* c1h = cpr + 16*592   + p*592;
        ushort* c0l = cpr + 16*592*2 + p*592;
        ushort* c1l = cpr + 16*592*3 + p*592;
        int x1 = 288 - m;
        c0h[x1] = hi;  c0l[x1] = lo;
        c1h[x1-1] = hi; c1l[x1-1] = lo;
        if (m >= 1){
            int x2 = 576 - m;
            c0h[x2] = hi;  c0l[x2] = lo;
            c1h[x2-1] = hi; c1l[x2-1] = lo;
        } else {
            c0h[0] = hi; c0l[0] = lo;
            csum[p] = san(1.0f + fw[(0*16 + p)*2 + 0], -1e4f, 1e4f);
        }
        return;
    }
    // ---- Xt: block per (bs,q) ----
    int id2 = (int)blockIdx.x - nc;       // 0..63
    int bs = id2 >> 4, q = id2 & 15;
    int tid = threadIdx.x;
    for (int e = tid; e < 32*196; e += 256){
        int a = e / 196, yx = e % 196;
        float v = pose[(bs*512 + a*16 + q)*196 + yx];   // coalesced along yx
        __hip_bfloat16 hb = __float2bfloat16(san(v, -1e4f, 1e4f));
        pl[a][yx] = *(ushort*)&hb;
    }
    __syncthreads();
    for (int idx = tid; idx < 49*9*4; idx += 256){
        int l = idx / 36, r2 = idx % 36, kk = r2 >> 2, a8 = r2 & 3;
        int oy = l / 7, ox = l % 7;
        int y = oy*2 - 1 + kk/3, x = ox*2 - 1 + kk%3;
        int cc = (bs*49 + l)*16 + q;
        union { ushort us8[8]; uint4 u4; } res;
        if ((unsigned)y < 14u && (unsigned)x < 14u){
            int yx = y*14 + x;
            #pragma unroll
            for (int u = 0; u < 8; ++u) res.us8[u] = pl[a8*8 + u][yx];
        } else {
            res.u4.x = 0; res.u4.y = 0; res.u4.z = 0; res.u4.w = 0;
        }
        *(uint4*)&Xt[cc*KKA_ + kk*32 + a8*8] = res.u4;  // 16B-aligned vector store
    }
}

// ================= K2: MEGA — 1024 threads, round-0 group phasing, clean allocator =================
// Round-8 was an infrastructure failure (container died before/independent of the
// kernel); source audited: no OOB, no divergent barriers, LDS < 160 KiB. Re-running
// the controlled TLP experiment with the standard __launch_bounds__(1024, 4) spelling
// (min 4 waves/EU -> 128-VGPR budget) instead of amdgpu_waves_per_eu(4,4).
//  - EM phases per 32-i super-group (round-0 A/B/C phasing, 2 barriers each): the
//    group's v is loaded ONCE into uu[8] registers and held through phase C ->
//    one v read per group per iteration (round 0's traffic discipline).
//  - v split: chunks 0..6 in LDS (114.7 KB), 7..17 in global (35 MB ws, streaming).
//  - GEMM: wave w owns p_g = w (16 waves, half the per-wave MFMA chain).
// LDS total 151.5 KB. Halves h=0/1 split pairs in phase 1 and groups in EM;
// cross-half combines via tred (round-7-proven, absmax-identical pattern).
__launch_bounds__(1024, 4)
__global__ void
k_mega(const ushort* __restrict__ cpr, const __hip_bfloat16* __restrict__ Xt,
       const float* __restrict__ a_in,
       const float* __restrict__ mpw, const float* __restrict__ mpb,
       const float* __restrict__ csum,
       const float* __restrict__ beta_u, const float* __restrict__ beta_a,
       uint* __restrict__ vg,
       float* __restrict__ out)
{
    const int nl = blockIdx.x;          // site
    const int t = threadIdx.x;          // 0..1023
    const int c = t & 511;              // v column = (Bc,p)
    const int h = t >> 9;               // half
    const int Bc = c >> 4, p = c & 15;
    const int bs = nl / L_, l = nl % L_;

    __shared__ __align__(16) _Float16 us[2*4224];   //  16896 B: GEMM double buffer
    __shared__ uint v_lds[56][512];                 // 114688 B: v pairs chunks 0..6
    __shared__ float d_s[32][33];                   //   4224 B
    __shared__ float rbuf[32][33];                  //   4224 B
    __shared__ float a_s[KKA_];                     //   1152 B
    __shared__ float cst[32];                       //    128 B
    __shared__ float tred[3*512];                   //   6144 B
    __shared__ float mub[512];                      //   2048 B
    __shared__ float i2b[512];                      //   2048 B  => 151552 B total

    uint* const vgs_em = vg + (long)nl*88*512;      // v pairs chunks 7..17 (88 rows)

    // unfold this site's activation row
    for (int j = t; j < KKA_; j += 1024){
        int kk = j >> 5, a = j & 31;
        int oy = l / OH_, ox = l % OH_;
        int y = oy*2 - 1 + kk/3, x = ox*2 - 1 + kk%3;
        float v = 0.f;
        if ((unsigned)y < 14u && (unsigned)x < 14u)
            v = a_in[((bs*A_ + a)*14 + y)*14 + x];
        a_s[j] = san(v, 0.f, 1e4f);
    }
    // per-thread weight row as packed fp16 (column c)
    half2v w_h[8];
    #pragma unroll
    for (int k = 0; k < 8; ++k){
        w_h[k].x = (_Float16)mpw[c*16 + 2*k];
        w_h[k].y = (_Float16)mpw[c*16 + 2*k + 1];
    }
    const float vb = mpb[c] * csum[p];  // bias pushed through the filter
    const float bu = beta_u[Bc];
    const float ba = beta_a[Bc];
    __syncthreads();                    // a_s ready

    // S0tot: 4 accumulators to shorten the dependent-add chain
    float s0a = 0.f, s0b = 0.f, s0c = 0.f, s0d = 0.f;
    for (int j = 0; j < KKA_; j += 4){
        s0a += a_s[j]; s0b += a_s[j+1]; s0c += a_s[j+2]; s0d += a_s[j+3];
    }
    const float S0tot = (s0a + s0b) + (s0c + s0d);

    // ---- GEMM lane mapping: wave w (0..15) owns p_g = w ----
    const int pg = t >> 6, lane = t & 63;
    const int mn = lane & 15, quad = lane >> 4;
    const __hip_bfloat16* xrow = Xt + (nl*16 + mn)*KKA_ + quad*8;

    float S1 = 0.f, S2 = 0.f;

    auto do_chunk = [&](int ch, _Float16* usb){
        floatx4 acc = {0,0,0,0};
        for (int k0i = 0; k0i < 9; ++k0i){
            const int k0 = k0i*32;
            short8 bfrag = *(const short8*)&xrow[k0];
            int o = 288 + k0 + quad*8 - (ch*16 + mn);
            int sel = o & 1, off = o - sel;
            const ushort* bh = cpr + (sel ? 16*592 : 0) + pg*592;
            const ushort* bl = cpr + 16*592*2 + (sel ? 16*592 : 0) + pg*592;
            short8 ah = *(const short8*)&bh[off];
            short8 al = *(const short8*)&bl[off];
            acc = __builtin_amdgcn_mfma_f32_16x16x32_bf16(ah, bfrag, acc, 0, 0, 0);
            acc = __builtin_amdgcn_mfma_f32_16x16x32_bf16(al, bfrag, acc, 0, 0, 0);
        }
        #pragma unroll
        for (int r = 0; r < 4; ++r)
            usb[pg*264 + (quad*4 + r)*16 + mn] = (_Float16)acc[r];
    };

    auto vpair = [&](const _Float16* urow, int s, float& v0o, float& v1o){
        union { uint4 u4; half2v h2[4]; } A0, A1, B0, B1;
        A0.u4 = *(const uint4*)&urow[(2*s)*16];
        A1.u4 = *(const uint4*)&urow[(2*s)*16 + 8];
        B0.u4 = *(const uint4*)&urow[(2*s+1)*16];
        B1.u4 = *(const uint4*)&urow[(2*s+1)*16 + 8];
        float v0 = vb, v1 = vb;
        #pragma unroll
        for (int m = 0; m < 4; ++m){
            v0 = dot2acc(A0.h2[m], w_h[m],   v0);
            v0 = dot2acc(A1.h2[m], w_h[4+m], v0);
            v1 = dot2acc(B0.h2[m], w_h[m],   v1);
            v1 = dot2acc(B1.h2[m], w_h[4+m], v1);
        }
        v0o = v0; v1o = v1;
    };

    // ---- phase 1: 18 chunks, double-buffered us, ONE barrier per chunk ----
    for (int ch = 0; ch < 18; ++ch){
        _Float16* usb = us + (ch & 1)*4224;
        do_chunk(ch, usb);
        __syncthreads();                            // us chunk ready
        const _Float16* urow = &usb[p*264];
        #pragma unroll
        for (int s4 = 0; s4 < 4; ++s4){
            const int s = h*4 + s4;                 // this half's pairs
            float v0, v1; vpair(urow, s, v0, v1);
            const int i0 = ch*16 + 2*s;
            const float a0 = a_s[i0], a1 = a_s[i0+1];
            S1 += a0*v0 + a1*v1;
            S2 += a0*v0*v0 + a1*v1*v1;
            union { half2v hh; uint u; } cv;
            cv.hh.x = (_Float16)v0; cv.hh.y = (_Float16)v1;
            if (ch < 7) v_lds[ch*8 + s][c] = cv.u;
            else        vgs_em[((ch-7)*8 + s)*512 + c] = cv.u;
        }
    }

    // iter-1 m-step (r = 1/32 exactly); combine halves via tred, publish mu/i2s
    if (h == 1){ tred[c] = S1; tred[512 + c] = S2; }
    __syncthreads();
    if (h == 0){
        const float S1t = S1 + tred[c];
        const float S2t = S2 + tred[512 + c];
        const float rs  = S0tot * (1.0f/32.0f);
        const float inv = 1.0f / (rs + 1e-12f);
        const float S1r = S1t * (1.0f/32.0f), S2r = S2t * (1.0f/32.0f);
        const float mu  = S1r * inv;
        const float sg  = fmaxf((S2r - 2.f*mu*S1r + mu*mu*rs) * inv, 0.f) + 1e-12f;
        const float lg  = logf(sg);
        float cs = (bu + 0.5f*lg) * rs;
        float ls = lg + LOG_LN2PI;
        #pragma unroll
        for (int m = 1; m < 16; m <<= 1){ cs += __shfl_xor(cs, m, 16); ls += __shfl_xor(ls, m, 16); }
        const float aout = san(1.f/(1.f + expf(-LAM1*(ba - cs))), 1e-30f, 1.f);
        if (p == 0) cst[Bc] = logf(aout) - 0.5f*ls;
        mub[c] = mu; i2b[c] = 0.5f/sg;
    }
    __syncthreads();                    // publish cst + mu/i2s
    float mu_r = mub[c], i2s_r = i2b[c];

    // ---- iterations 2,3: per-super-group A/B/C (v held in uu regs from A to C) ----
    const int b0 = p & 1, b1 = (p>>1)&1, b2 = (p>>2)&1, b3 = (p>>3)&1;
    const int isub = t >> 5, Bce = t & 31;
    float muF = 0.f, aF = 0.f;
    for (int it = 0; it < 2; ++it){
        const float lam = it ? LAM3 : LAM2;
        float T0 = 0.f, T1 = 0.f, T2 = 0.f;

        for (int sg = 0; sg < 9; ++sg){
            const int g = 2*sg + h;                 // this half's group (16 i)
            // load group's v pairs once; held through phase C
            uint uu[8];
            #pragma unroll
            for (int s = 0; s < 8; ++s)
                uu[s] = (g < 7) ? v_lds[g*8 + s][c]
                                : vgs_em[((g-7)*8 + s)*512 + c];

            // ---- phase A: d(i,Bc) via round-0 4-level tree; lane p -> i = g*16+p ----
            {
                float e1[8], e2[4], e3[2], dfin;
                #pragma unroll
                for (int s = 0; s < 8; ++s){
                    union { uint u; half2v hh; } cv; cv.u = uu[s];
                    float v0 = (float)cv.hh.x, v1 = (float)cv.hh.y;
                    float d0 = v0 - mu_r, d1 = v1 - mu_r;
                    float ea = d0*d0*i2s_r, eb = d1*d1*i2s_r;
                    float aown  = b0 ? eb : ea;
                    float asend = b0 ? ea : eb;
                    e1[s] = aown + __shfl_xor(asend, 1);
                }
                #pragma unroll
                for (int s = 0; s < 4; ++s){
                    float aown  = b1 ? e1[2*s+1] : e1[2*s];
                    float asend = b1 ? e1[2*s]   : e1[2*s+1];
                    e2[s] = aown + __shfl_xor(asend, 2);
                }
                #pragma unroll
                for (int s = 0; s < 2; ++s){
                    float aown  = b2 ? e2[2*s+1] : e2[2*s];
                    float asend = b2 ? e2[2*s]   : e2[2*s+1];
                    e3[s] = aown + __shfl_xor(asend, 4);
                }
                {
                    float aown  = b3 ? e3[1] : e3[0];
                    float asend = b3 ? e3[0] : e3[1];
                    dfin = aown + __shfl_xor(asend, 8);
                }
                d_s[h*16 + p][Bc] = dfin;           // row = local i = h*16 + p
            }
            __syncthreads();                        // (1) d_s ready (32 rows)

            // ---- phase B: softmax over B for 32 i-rows; thread -> (isub, Bce) ----
            {
                const float cb = cst[Bce];
                float lnap = cb - d_s[isub][Bce];
                float mx = lnap;
                #pragma unroll
                for (int m = 16; m >= 1; m >>= 1) mx = fmaxf(mx, __shfl_xor(mx, m));
                float ex = expf(lnap - mx);
                float sm = ex;
                #pragma unroll
                for (int m = 16; m >= 1; m >>= 1) sm += __shfl_xor(sm, m);
                rbuf[isub][Bce] = (ex / sm) * a_s[sg*32 + isub];
            }
            __syncthreads();                        // (2) rbuf ready

            // ---- phase C: T sums for this group (v from uu regs) ----
            #pragma unroll
            for (int s = 0; s < 8; ++s){
                union { uint u; half2v hh; } cv; cv.u = uu[s];
                float v0 = (float)cv.hh.x, v1 = (float)cv.hh.y;
                float r0 = rbuf[h*16 + 2*s][Bc];
                float r1 = rbuf[h*16 + 2*s + 1][Bc];
                T0 += r0 + r1;
                T1 += r0*v0 + r1*v1;
                T2 += r0*v0*v0 + r1*v1*v1;
            }
            // next sg's A writes d_s, B writes rbuf only after barriers -> safe
        }

        // combine T halves + m-step
        if (h == 1){ tred[c] = T0; tred[512 + c] = T1; tred[1024 + c] = T2; }
        __syncthreads();
        if (h == 0){
            T0 += tred[c]; T1 += tred[512 + c]; T2 += tred[1024 + c];
            const float inv = 1.f/(T0 + 1e-12f);
            const float mu  = T1 * inv;
            const float sg  = fmaxf((T2 - 2.f*mu*T1 + mu*mu*T0) * inv, 0.f) + 1e-12f;
            const float lg  = logf(sg);
            float cs = (bu + 0.5f*lg) * T0;
            float ls = lg + LOG_LN2PI;
            #pragma unroll
            for (int m = 1; m < 16; m <<= 1){ cs += __shfl_xor(cs, m, 16); ls += __shfl_xor(ls, m, 16); }
            const float aout = san(1.f/(1.f + expf(-lam*(ba - cs))), 1e-30f, 1.f);
            if (it == 0){
                mub[c] = mu; i2b[c] = 0.5f/sg;
                if (p == 0) cst[Bc] = logf(aout) - 0.5f*ls;
            } else { muF = mu; aF = aout; }
        }
        __syncthreads();                            // publish mu/i2s/cst; tred reuse safe
        if (it == 0){ mu_r = mub[c]; i2s_r = i2b[c]; }
    }

    // ---- outputs (fp32): [a_fin 4*32*49][pose_out 4*512*49] ----
    if (h == 0){
        if (p == 0) out[bs*(B_*L_) + Bc*L_ + l] = san(aF, 0.f, 1.f);
        out[6272 + (bs*512 + c)*L_ + l] = san(muF, -1e4f, 1e4f);
    }
}

// ================= launch =================
extern "C" void kernel_launch(void* const* d_in, const int* in_sizes, int n_in,
                              void* d_out, int out_size, void* d_ws, size_t ws_size,
                              hipStream_t stream)
{
    const float* a_in   = (const float*)d_in[0];
    const float* pose   = (const float*)d_in[1];
    const float* mpw    = (const float*)d_in[2];
    const float* mpb    = (const float*)d_in[3];
    const float* fw     = (const float*)d_in[4];
    // d_in[5..8] (ln_g, ln_b, spat_w, spat_bias) are provably dead: softmax over B of a
    // B-independent gate is exactly 1/B regardless of their values.
    const float* beta_u = (const float*)d_in[9];
    const float* beta_a = (const float*)d_in[10];
    float* out = (float*)d_out;

    // ---- ws layout (byte offsets) ----
    // csum [16] f32             @ 0        (64 B)
    // cpr  4x[16][592] u16      @ 256      (75776 B)
    // Xt   [3136][288] bf16     @ 76288    (1806336 B)
    // vglob [196][88][512] uint @ 1882624  (35323904 B)  -> total ~37.2 MB
    char* base = (char*)d_ws;
    float*  csum = (float*)(base + 0);
    ushort* cpr  = (ushort*)(base + 256);
    __hip_bfloat16* Xt = (__hip_bfloat16*)(base + 76288);
    uint*   vg   = (uint*)(base + 1882624);

    const int nc = 18;
    k_prep<<<nc + 64, 256, 0, stream>>>(fw, pose, cpr, csum, Xt, nc);
    k_mega<<<NSITE, 1024, 0, stream>>>(cpr, Xt, a_in, mpw, mpb, csum, beta_u, beta_a, vg, out);
}